// Round 5
// baseline (248.058 us; speedup 1.0000x reference)
//
#include <hip/hip_runtime.h>
#include <hip/hip_bf16.h>
#include <hip/hip_cooperative_groups.h>

namespace cg = cooperative_groups;

#define NMOL 1024
#define MOLSIZE 128

// Output layout (all float32, reference return order, flat):
// [0] nmol, [1] molsize, [2..2+1024) nHeavy, [1026..2050) nHydro, [2050..3074) nocc,
// [3074 +0/1/2*n_real) Z, maskd, atom_molid,
// P=3074+3*n_real: mask, pair_molid, ni, nj, idxi, idxj (np each), xij (3*np), rij (np)

// Exact-reference arithmetic: f32 sub, (x^2+y^2)+z^2 without fma, sqrt.
__device__ __forceinline__ float pair_dist(float ax, float ay, float az,
                                           float bx, float by, float bz,
                                           float& dx, float& dy, float& dz) {
    dx = __fsub_rn(bx, ax);
    dy = __fsub_rn(by, ay);
    dz = __fsub_rn(bz, az);
    float d2 = __fadd_rn(__fadd_rn(__fmul_rn(dx, dx), __fmul_rn(dy, dy)), __fmul_rn(dz, dz));
    return __fsqrt_rn(d2);
}

__global__ __launch_bounds__(256) void k_fused(const int* __restrict__ species,
                                               const float* __restrict__ coord,
                                               const float* __restrict__ tore,
                                               float* __restrict__ out,
                                               int* __restrict__ cnt_real,
                                               int* __restrict__ pair_tot,
                                               int* __restrict__ mol_base,
                                               int* __restrict__ pair_mol_base) {
    cg::grid_group grid = cg::this_grid();
    __shared__ float cx[MOLSIZE], cy[MOLSIZE], cz[MOLSIZE], spf[MOLSIZE];
    __shared__ int iv[MOLSIZE];
    __shared__ unsigned long long bal_s[256];
    __shared__ int sIncl[256];
    __shared__ int sH[2], sY[2], sN[2];
    __shared__ float sT[2];
    __shared__ int wpair[4], wt[4], wtot[4];
    __shared__ int wc0s;

    int m = blockIdx.x, t = threadIdx.x;
    int lane = t & 63, w = t >> 6;

    // ---------------- Phase A: load + mol stats + ballots (LDS-resident) ----------------
    int s_at = 0;
    unsigned long long amb = 0ull;
    if (t < MOLSIZE) {  // waves 0,1 fully active: ballots are wave-uniform
        int f = m * MOLSIZE + t;
        s_at = species[f];
        bool nb = (s_at > 0);
        float x = coord[3 * f + 0], y = coord[3 * f + 1], z = coord[3 * f + 2];
        float sent = 1.0e30f * (float)(t + 1);  // blanks -> dist = inf, never selected
        cx[t] = nb ? x : sent;
        cy[t] = nb ? y : sent;
        cz[t] = nb ? z : sent;
        spf[t] = (float)s_at;
        amb = __ballot(nb);
        if (t == 0) wc0s = __popcll(amb);
        int h = (s_at > 1) ? 1 : 0, yy = (s_at == 1) ? 1 : 0, nn = nb ? 1 : 0;
        float tv = tore[s_at];  // integer-valued: reduction order exact
        for (int d = 32; d > 0; d >>= 1) {
            h += __shfl_down(h, d);
            yy += __shfl_down(yy, d);
            nn += __shfl_down(nn, d);
            tv += __shfl_down(tv, d);
        }
        if (lane == 0) { sH[w] = h; sY[w] = yy; sN[w] = nn; sT[w] = tv; }
    }
    __syncthreads();
    if (t == 0) {
        out[2 + m] = (float)(sH[0] + sH[1]);
        out[2 + NMOL + m] = (float)(sY[0] + sY[1]);
        out[2 + 2 * NMOL + m] = (float)((int)((sT[0] + sT[1]) * 0.5f));
        cnt_real[m] = sN[0] + sN[1];
        if (m == 0) { out[0] = (float)NMOL; out[1] = (float)MOLSIZE; }
    }
    // pair sweep: wave w handles rows a = w, w+4, ...; chunk c = 2a + (b>=64), bit = b&63
    float bxl = cx[lane], byl = cy[lane], bzl = cz[lane];
    float bxh = cx[64 + lane], byh = cy[64 + lane], bzh = cz[64 + lane];
    int wcount = 0;
    for (int j = 0; j < 32; ++j) {
        int a = w + 4 * j;
        float ax = cx[a], ay = cy[a], az = cz[a];  // broadcast reads
        unsigned long long mb0 = 0ull, mb1 = 0ull;
        if (a < 63) {  // lo half: b = lane, need b > a
            float dx, dy, dz;
            float dist = pair_dist(ax, ay, az, bxl, byl, bzl, dx, dy, dz);
            mb0 = __ballot((lane > a) && (dist < 5.0f));
        }
        if (a < 127) {  // hi half: b = 64+lane, need b > a (matters for a >= 64!)
            float dx, dy, dz;
            float dist = pair_dist(ax, ay, az, bxh, byh, bzh, dx, dy, dz);
            mb1 = __ballot(((64 + lane) > a) && (dist < 5.0f));
        }
        if (lane == 0) { bal_s[2 * a] = mb0; bal_s[2 * a + 1] = mb1; }
        wcount += __popcll(mb0) + __popcll(mb1);
    }
    if (lane == 0) wpair[w] = wcount;
    __syncthreads();  // bal_s + wpair visible block-wide
    if (t == 0) pair_tot[m] = wpair[0] + wpair[1] + wpair[2] + wpair[3];
    __threadfence();
    grid.sync();

    // ---------------- Phase B: two 1024-element exclusive scans (blocks 0,1) ----------------
    if (m < 2) {
        const int* cnt = m ? pair_tot : cnt_real;
        int* base = m ? pair_mol_base : mol_base;
        int v0 = cnt[4 * t + 0], v1 = cnt[4 * t + 1], v2 = cnt[4 * t + 2], v3 = cnt[4 * t + 3];
        int s = v0 + v1 + v2 + v3;
        int v = s;
        for (int d = 1; d < 64; d <<= 1) {
            int u = __shfl_up(v, d);
            if (lane >= d) v += u;
        }
        if (lane == 63) wt[w] = v;
        __syncthreads();  // block-uniform branch: safe
        int add = 0;
        for (int ww = 0; ww < w; ++ww) add += wt[ww];
        int incl = v + add, excl = incl - s;
        base[4 * t + 0] = excl;
        base[4 * t + 1] = excl + v0;
        base[4 * t + 2] = excl + v0 + v1;
        base[4 * t + 3] = excl + v0 + v1 + v2;
        if (t == 255) base[1024] = incl;
        __threadfence();
    }
    grid.sync();

    // ---------------- Phase C: atom outputs + dense pair scatter ----------------
    int n_real = mol_base[NMOL];
    int npairs = pair_mol_base[NMOL];
    int cval = __popcll(bal_s[t]);
    int v = cval;
    for (int d = 1; d < 64; d <<= 1) {
        int u = __shfl_up(v, d);
        if (lane >= d) v += u;
    }
    if (lane == 63) wtot[w] = v;
    __syncthreads();
    if (t < MOLSIZE && s_at > 0) {  // s_at/amb live in registers from Phase A
        int rank = __popcll(amb & ((1ull << lane) - 1ull)) + ((w == 1) ? wc0s : 0);
        int g = mol_base[m] + rank;
        iv[t] = g;
        out[3074 + g] = (float)s_at;
        out[3074 + n_real + g] = (float)(t * (MOLSIZE + 1) + m * (MOLSIZE * MOLSIZE));
        out[3074 + 2 * n_real + g] = (float)m;
    }
    int add = 0;
    for (int ww = 0; ww < w; ++ww) add += wtot[ww];
    sIncl[t] = v + add;
    __syncthreads();  // iv + sIncl visible
    int np_mol = sIncl[255];

    int offP = 3074 + 3 * n_real;
    float* pm0 = out + offP;
    float* pm1 = pm0 + npairs;
    float* pm2 = pm1 + npairs;
    float* pm3 = pm2 + npairs;
    float* pm4 = pm3 + npairs;
    float* pm5 = pm4 + npairs;
    float* px  = pm5 + npairs;
    float* pr  = px + 3 * npairs;
    int qbase = pair_mol_base[m];
    float fm = (float)m;

    for (int q = t; q < np_mol; q += 256) {
        // binary search: c = first chunk with inclusive-scan > q
        int c = 0;
        if (sIncl[c + 127] <= q) c += 128;
        if (sIncl[c + 63] <= q) c += 64;
        if (sIncl[c + 31] <= q) c += 32;
        if (sIncl[c + 15] <= q) c += 16;
        if (sIncl[c + 7] <= q) c += 8;
        if (sIncl[c + 3] <= q) c += 4;
        if (sIncl[c + 1] <= q) c += 2;
        if (sIncl[c] <= q) c += 1;
        int r = q - (c ? sIncl[c - 1] : 0);
        unsigned long long mb = bal_s[c];
        // branchless select of r-th set bit
        unsigned int cur = (unsigned int)mb;
        int idx = 0;
        int cc = __popc(cur);
        if (r >= cc) { r -= cc; idx = 32; cur = (unsigned int)(mb >> 32); }
        cc = __popc(cur & 0xFFFFu); if (r >= cc) { r -= cc; idx += 16; cur >>= 16; }
        cc = __popc(cur & 0xFFu);   if (r >= cc) { r -= cc; idx += 8;  cur >>= 8; }
        cc = __popc(cur & 0xFu);    if (r >= cc) { r -= cc; idx += 4;  cur >>= 4; }
        cc = __popc(cur & 0x3u);    if (r >= cc) { r -= cc; idx += 2;  cur >>= 2; }
        cc = cur & 1u;              if (r >= cc) { idx += 1; }
        int a = c >> 1;
        int b = ((c & 1) << 6) | idx;
        float dx, dy, dz;
        float dist = pair_dist(cx[a], cy[a], cz[a], cx[b], cy[b], cz[b], dx, dy, dz);
        int Q = qbase + q;
        pm0[Q] = (float)(m * (MOLSIZE * MOLSIZE) + a * MOLSIZE + b);
        pm1[Q] = fm;
        pm2[Q] = spf[a];
        pm3[Q] = spf[b];
        pm4[Q] = (float)iv[a];
        pm5[Q] = (float)iv[b];
        px[3 * Q + 0] = __fdiv_rn(dx, dist);
        px[3 * Q + 1] = __fdiv_rn(dy, dist);
        px[3 * Q + 2] = __fdiv_rn(dz, dist);
        pr[Q] = __fmul_rn(dist, 1.8897261258369282f);
    }
}

extern "C" void kernel_launch(void* const* d_in, const int* in_sizes, int n_in,
                              void* d_out, int out_size, void* d_ws, size_t ws_size,
                              hipStream_t stream) {
    const int* species = (const int*)d_in[0];
    const float* coords = (const float*)d_in[1];
    const float* tore = (const float*)d_in[2];
    float* out = (float*)d_out;
    int* ws = (int*)d_ws;

    int* cnt_real      = ws;            // 1024
    int* pair_tot      = ws + 1024;     // 1024
    int* mol_base      = ws + 2048;     // 1025
    int* pair_mol_base = ws + 3073;     // 1025

    void* args[] = {(void*)&species, (void*)&coords, (void*)&tore, (void*)&out,
                    (void*)&cnt_real, (void*)&pair_tot, (void*)&mol_base, (void*)&pair_mol_base};
    hipLaunchCooperativeKernel((void*)k_fused, dim3(NMOL), dim3(256), args, 0, stream);
}

// Round 6
// 79.369 us; speedup vs baseline: 3.1254x; 3.1254x over previous
//
#include <hip/hip_runtime.h>
#include <hip/hip_bf16.h>

#define NMOL 1024
#define MOLSIZE 128

// Output layout (all float32, reference return order, flat):
// [0] nmol, [1] molsize, [2..2+1024) nHeavy, [1026..2050) nHydro, [2050..3074) nocc,
// [3074 +0/1/2*n_real) Z, maskd, atom_molid,
// P=3074+3*n_real: mask, pair_molid, ni, nj, idxi, idxj (np each), xij (3*np), rij (np)
//
// Structure note (R5 post-mortem): cooperative grid.sync() costs ~80us/sync on
// gfx950 at 1024 blocks — multi-launch (~2-3us each) is strictly better for the
// two global dependencies here. 2 launches: count -> scatter (scatter blocks
// redundantly compute the 1024-wide prefix sums from L2-resident count arrays).

// Exact-reference arithmetic: f32 sub, (x^2+y^2)+z^2 without fma, sqrt.
__device__ __forceinline__ float pair_dist(float ax, float ay, float az,
                                           float bx, float by, float bz,
                                           float& dx, float& dy, float& dz) {
    dx = __fsub_rn(bx, ax);
    dy = __fsub_rn(by, ay);
    dz = __fsub_rn(bz, az);
    float d2 = __fadd_rn(__fadd_rn(__fmul_rn(dx, dx), __fmul_rn(dy, dy)), __fmul_rn(dz, dz));
    return __fsqrt_rn(d2);
}

// ---------- K1: mol stats + per-chunk ballots (chunk c = 2*a + (b>=64), bit = b&63) ----------
__global__ __launch_bounds__(256) void k_count(const int* __restrict__ species,
                                               const float* __restrict__ coord,
                                               const float* __restrict__ tore,
                                               float* __restrict__ out,
                                               int* __restrict__ cnt_real,
                                               int* __restrict__ pair_tot,
                                               unsigned long long* __restrict__ bal_g) {
    __shared__ float cx[MOLSIZE], cy[MOLSIZE], cz[MOLSIZE];
    __shared__ unsigned long long bal_s[256];
    __shared__ int sH[2], sY[2], sN[2];
    __shared__ float sT[2];
    __shared__ int wpair[4];
    int m = blockIdx.x, t = threadIdx.x;
    int lane = t & 63, w = t >> 6;
    if (t < MOLSIZE) {
        int f = m * MOLSIZE + t;
        int s = species[f];
        bool nb = (s > 0);
        float x = coord[3 * f + 0], y = coord[3 * f + 1], z = coord[3 * f + 2];
        float sent = 1.0e30f * (float)(t + 1);  // blanks -> dist = inf, never selected
        cx[t] = nb ? x : sent;
        cy[t] = nb ? y : sent;
        cz[t] = nb ? z : sent;
        int h = (s > 1) ? 1 : 0, yy = (s == 1) ? 1 : 0, nn = nb ? 1 : 0;
        float tv = tore[s];  // integer-valued: reduction order exact
        for (int d = 32; d > 0; d >>= 1) {
            h += __shfl_down(h, d);
            yy += __shfl_down(yy, d);
            nn += __shfl_down(nn, d);
            tv += __shfl_down(tv, d);
        }
        if (lane == 0) { sH[w] = h; sY[w] = yy; sN[w] = nn; sT[w] = tv; }
    }
    __syncthreads();
    if (t == 0) {
        out[2 + m] = (float)(sH[0] + sH[1]);
        out[2 + NMOL + m] = (float)(sY[0] + sY[1]);
        out[2 + 2 * NMOL + m] = (float)((int)((sT[0] + sT[1]) * 0.5f));
        cnt_real[m] = sN[0] + sN[1];
        if (m == 0) { out[0] = (float)NMOL; out[1] = (float)MOLSIZE; }
    }
    // pair sweep: wave w handles rows a = w, w+4, ...
    float bxl = cx[lane], byl = cy[lane], bzl = cz[lane];
    float bxh = cx[64 + lane], byh = cy[64 + lane], bzh = cz[64 + lane];
    int wcount = 0;
    for (int j = 0; j < 32; ++j) {
        int a = w + 4 * j;
        float ax = cx[a], ay = cy[a], az = cz[a];  // broadcast reads
        unsigned long long mb0 = 0ull, mb1 = 0ull;
        if (a < 63) {  // lo half: b = lane, need b > a
            float dx, dy, dz;
            float dist = pair_dist(ax, ay, az, bxl, byl, bzl, dx, dy, dz);
            mb0 = __ballot((lane > a) && (dist < 5.0f));
        }
        if (a < 127) {  // hi half: b = 64+lane, need b > a (matters for a >= 64!)
            float dx, dy, dz;
            float dist = pair_dist(ax, ay, az, bxh, byh, bzh, dx, dy, dz);
            mb1 = __ballot(((64 + lane) > a) && (dist < 5.0f));
        }
        if (lane == 0) { bal_s[2 * a] = mb0; bal_s[2 * a + 1] = mb1; }
        wcount += __popcll(mb0) + __popcll(mb1);
    }
    if (lane == 0) wpair[w] = wcount;
    __syncthreads();
    if (t == 0) pair_tot[m] = wpair[0] + wpair[1] + wpair[2] + wpair[3];
    bal_g[m * 256 + t] = bal_s[t];  // coalesced 2KB store
}

// ---------- K2: atom outputs + dense pair scatter (per-block redundant prefix) ----------
__global__ __launch_bounds__(256) void k_scatter(const int* __restrict__ species,
                                                 const float* __restrict__ coord,
                                                 const int* __restrict__ cnt_real,
                                                 const int* __restrict__ pair_tot,
                                                 const unsigned long long* __restrict__ bal_g,
                                                 float* __restrict__ out) {
    __shared__ float cx[MOLSIZE], cy[MOLSIZE], cz[MOLSIZE], spf[MOLSIZE];
    __shared__ int iv[MOLSIZE];
    __shared__ unsigned long long bal_s[256];
    __shared__ int sIncl[256];
    __shared__ int wtot[4];
    __shared__ int redALT[4], redAALL[4], redPLT[4], redPALL[4];
    __shared__ int wc0s;
    int m = blockIdx.x, t = threadIdx.x;
    int lane = t & 63, w = t >> 6;

    unsigned long long bal = bal_g[m * 256 + t];
    bal_s[t] = bal;

    // redundant global prefix: thread t covers indices 4t..4t+3 of both count arrays
    int4 ca = ((const int4*)cnt_real)[t];
    int4 cp = ((const int4*)pair_tot)[t];
    int i0 = 4 * t;
    int aLT = ((i0 + 0) < m ? ca.x : 0) + ((i0 + 1) < m ? ca.y : 0) +
              ((i0 + 2) < m ? ca.z : 0) + ((i0 + 3) < m ? ca.w : 0);
    int aALL = ca.x + ca.y + ca.z + ca.w;
    int pLT = ((i0 + 0) < m ? cp.x : 0) + ((i0 + 1) < m ? cp.y : 0) +
              ((i0 + 2) < m ? cp.z : 0) + ((i0 + 3) < m ? cp.w : 0);
    int pALL = cp.x + cp.y + cp.z + cp.w;
    for (int d = 32; d > 0; d >>= 1) {
        aLT += __shfl_down(aLT, d);
        aALL += __shfl_down(aALL, d);
        pLT += __shfl_down(pLT, d);
        pALL += __shfl_down(pALL, d);
    }
    if (lane == 0) { redALT[w] = aLT; redAALL[w] = aALL; redPLT[w] = pLT; redPALL[w] = pALL; }

    int s_at = 0;
    unsigned long long amb = 0ull;
    if (t < MOLSIZE) {
        int f = m * MOLSIZE + t;
        s_at = species[f];
        cx[t] = coord[3 * f + 0];
        cy[t] = coord[3 * f + 1];
        cz[t] = coord[3 * f + 2];
        spf[t] = (float)s_at;
        amb = __ballot(s_at > 0);
        if (t == 0) wc0s = __popcll(amb);
    }
    // wave-level inclusive scan of chunk counts
    int v = __popcll(bal);
    int cval = v;
    for (int d = 1; d < 64; d <<= 1) {
        int u = __shfl_up(v, d);
        if (lane >= d) v += u;
    }
    (void)cval;
    if (lane == 63) wtot[w] = v;
    __syncthreads();

    int mol_base_m = redALT[0] + redALT[1] + redALT[2] + redALT[3];
    int n_real     = redAALL[0] + redAALL[1] + redAALL[2] + redAALL[3];
    int qbase      = redPLT[0] + redPLT[1] + redPLT[2] + redPLT[3];
    int npairs     = redPALL[0] + redPALL[1] + redPALL[2] + redPALL[3];

    // atom outputs
    if (t < MOLSIZE && s_at > 0) {
        int rank = __popcll(amb & ((1ull << lane) - 1ull)) + ((w == 1) ? wc0s : 0);
        int g = mol_base_m + rank;
        iv[t] = g;
        out[3074 + g] = (float)s_at;
        out[3074 + n_real + g] = (float)(t * (MOLSIZE + 1) + m * (MOLSIZE * MOLSIZE));
        out[3074 + 2 * n_real + g] = (float)m;
    }
    int add = 0;
    for (int ww = 0; ww < w; ++ww) add += wtot[ww];
    sIncl[t] = v + add;
    __syncthreads();  // iv + sIncl visible
    int np_mol = sIncl[255];

    int offP = 3074 + 3 * n_real;
    float* pm0 = out + offP;
    float* pm1 = pm0 + npairs;
    float* pm2 = pm1 + npairs;
    float* pm3 = pm2 + npairs;
    float* pm4 = pm3 + npairs;
    float* pm5 = pm4 + npairs;
    float* px  = pm5 + npairs;
    float* pr  = px + 3 * npairs;
    float fm = (float)m;

    for (int q = t; q < np_mol; q += 256) {
        // binary search: c = first chunk with inclusive-scan > q
        int c = 0;
        if (sIncl[c + 127] <= q) c += 128;
        if (sIncl[c + 63] <= q) c += 64;
        if (sIncl[c + 31] <= q) c += 32;
        if (sIncl[c + 15] <= q) c += 16;
        if (sIncl[c + 7] <= q) c += 8;
        if (sIncl[c + 3] <= q) c += 4;
        if (sIncl[c + 1] <= q) c += 2;
        if (sIncl[c] <= q) c += 1;
        int r = q - (c ? sIncl[c - 1] : 0);
        unsigned long long mb = bal_s[c];
        // branchless select of r-th set bit
        unsigned int cur = (unsigned int)mb;
        int idx = 0;
        int cc = __popc(cur);
        if (r >= cc) { r -= cc; idx = 32; cur = (unsigned int)(mb >> 32); }
        cc = __popc(cur & 0xFFFFu); if (r >= cc) { r -= cc; idx += 16; cur >>= 16; }
        cc = __popc(cur & 0xFFu);   if (r >= cc) { r -= cc; idx += 8;  cur >>= 8; }
        cc = __popc(cur & 0xFu);    if (r >= cc) { r -= cc; idx += 4;  cur >>= 4; }
        cc = __popc(cur & 0x3u);    if (r >= cc) { r -= cc; idx += 2;  cur >>= 2; }
        cc = cur & 1u;              if (r >= cc) { idx += 1; }
        int a = c >> 1;
        int b = ((c & 1) << 6) | idx;
        float dx, dy, dz;
        float dist = pair_dist(cx[a], cy[a], cz[a], cx[b], cy[b], cz[b], dx, dy, dz);
        int Q = qbase + q;
        pm0[Q] = (float)(m * (MOLSIZE * MOLSIZE) + a * MOLSIZE + b);
        pm1[Q] = fm;
        pm2[Q] = spf[a];
        pm3[Q] = spf[b];
        pm4[Q] = (float)iv[a];
        pm5[Q] = (float)iv[b];
        px[3 * Q + 0] = __fdiv_rn(dx, dist);
        px[3 * Q + 1] = __fdiv_rn(dy, dist);
        px[3 * Q + 2] = __fdiv_rn(dz, dist);
        pr[Q] = __fmul_rn(dist, 1.8897261258369282f);
    }
}

extern "C" void kernel_launch(void* const* d_in, const int* in_sizes, int n_in,
                              void* d_out, int out_size, void* d_ws, size_t ws_size,
                              hipStream_t stream) {
    const int* species = (const int*)d_in[0];
    const float* coords = (const float*)d_in[1];
    const float* tore = (const float*)d_in[2];
    float* out = (float*)d_out;
    int* ws = (int*)d_ws;

    int* cnt_real = ws;          // 1024 (16B aligned)
    int* pair_tot = ws + 1024;   // 1024 (16B aligned)
    unsigned long long* bal_g = (unsigned long long*)(ws + 2048);  // 2 MB

    k_count<<<NMOL, 256, 0, stream>>>(species, coords, tore, out, cnt_real, pair_tot, bal_g);
    k_scatter<<<NMOL, 256, 0, stream>>>(species, coords, cnt_real, pair_tot, bal_g, out);
}